// Round 4
// baseline (762.586 us; speedup 1.0000x reference)
//
#include <hip/hip_runtime.h>

#define BB 4
#define NN 4096
#define DD 256
#define KK 16
#define PTS 2

typedef __bf16 bf16;
typedef __attribute__((ext_vector_type(8))) __bf16 bf16x8;
typedef __attribute__((ext_vector_type(4))) __bf16 bf16x4;
typedef __attribute__((ext_vector_type(4))) float f32x4;

// ---------------------------------------------------------------------------
// Prep: weights -> bf16; pe_w padded [256][64]; zero bn accumulators (saves
// a separate memset dispatch).
// ---------------------------------------------------------------------------
__global__ __launch_bounds__(256) void prep_kernel(
    const float* __restrict__ wq, const float* __restrict__ wk,
    const float* __restrict__ wv, const float* __restrict__ w1,
    const float* __restrict__ w2, const float* __restrict__ pw,
    bf16* __restrict__ wqb, bf16* __restrict__ wkb, bf16* __restrict__ wvb,
    bf16* __restrict__ w1b, bf16* __restrict__ w2b, bf16* __restrict__ pwb,
    float* __restrict__ sums) {
  const int idx = blockIdx.x * 256 + threadIdx.x;  // 65536
  wqb[idx] = (bf16)wq[idx];
  wkb[idx] = (bf16)wk[idx];
  wvb[idx] = (bf16)wv[idx];
  w1b[idx] = (bf16)w1[idx];
  w2b[idx] = (bf16)w2[idx];
  if (idx < 256 * 64) {
    const int n = idx >> 6, c = idx & 63;
    pwb[idx] = (c < 33) ? (bf16)pw[n * 33 + c] : (bf16)0.f;
  }
  if (idx < 2 * DD) sums[idx] = 0.f;
}

// ---------------------------------------------------------------------------
// KNN: one wave per point, packed (distbits+1)<<32|j argmin rounds (verified
// R1-R3). ~150 VGPR (cand[64]); launch_bounds(256,2) caps at 256 - no spill.
// ---------------------------------------------------------------------------
__global__ __launch_bounds__(256, 2) void knn_v2(const float* __restrict__ xyz,
                                                 int* __restrict__ knn) {
  const int lane = threadIdx.x & 63;
  const int wv = threadIdx.x >> 6;
  const int row = blockIdx.x * 4 + wv;
  const int b = row >> 12, i = row & (NN - 1);
  const float* xb = xyz + (size_t)b * NN * 3;
  const float xi = xb[i * 3 + 0], yi = xb[i * 3 + 1], zi = xb[i * 3 + 2];
  unsigned long long cand[64];
#pragma unroll
  for (int c = 0; c < 64; ++c) {
    const int j = c * 64 + lane;
    const float dx = xi - xb[j * 3 + 0];
    const float dy = yi - xb[j * 3 + 1];
    const float dz = zi - xb[j * 3 + 2];
    const float d = dx * dx + dy * dy + dz * dz;
    const unsigned long long fb = (unsigned long long)(__float_as_uint(d)) + 1ull;
    cand[c] = (fb << 32) | (unsigned int)j;
  }
  unsigned long long lastkey = 0ull;
  unsigned int myj = 0u;
  for (int r = 0; r < KK; ++r) {
    unsigned long long lmin = ~0ull;
#pragma unroll
    for (int c = 0; c < 64; ++c) {
      const unsigned long long v = cand[c];
      if (v > lastkey && v < lmin) lmin = v;
    }
#pragma unroll
    for (int off = 1; off < 64; off <<= 1) {
      const unsigned long long o = __shfl_xor(lmin, off);
      if (o < lmin) lmin = o;
    }
    if (lane == r) myj = (unsigned int)lmin;
    lastkey = lmin;
  }
  if (lane < KK) knn[row * KK + lane] = (int)myj;
}

// ---------------------------------------------------------------------------
// proj MFMA (unchanged, est ~5-10 us): q fp32, k/v bf16.
// ---------------------------------------------------------------------------
__global__ __launch_bounds__(256, 4) void proj_mfma(
    const float* __restrict__ feats, const bf16* __restrict__ wqb,
    const bf16* __restrict__ wkb, const bf16* __restrict__ wvb,
    float* __restrict__ q, bf16* __restrict__ kfb, bf16* __restrict__ vfb) {
  const int t = threadIdx.x;
  const int lane = t & 63, wv = t >> 6;
  const int m = lane & 15, qd = lane >> 4;
  const size_t r0 = (size_t)blockIdx.x * 64;
  __shared__ __align__(16) bf16 fs[64][264];
  const float4* f4 = (const float4*)(feats + r0 * DD);
  for (int i = 0; i < 16; ++i) {
    const int e = i * 256 + t;
    const float4 v = f4[e];
    bf16x4 w;
    w[0] = (bf16)v.x; w[1] = (bf16)v.y; w[2] = (bf16)v.z; w[3] = (bf16)v.w;
    *(bf16x4*)&fs[e >> 6][(e & 63) * 4] = w;
  }
  __syncthreads();
  bf16x8 afrag[8];
#pragma unroll
  for (int f = 0; f < 8; ++f)
    afrag[f] = *(const bf16x8*)&fs[wv * 16 + m][f * 32 + qd * 8];
  const bf16* wmat[3] = {wqb, wkb, wvb};
  for (int mat = 0; mat < 3; ++mat) {
    const bf16* wb = wmat[mat];
    for (int nt = 0; nt < 16; ++nt) {
      const int n = nt * 16 + m;
      bf16x8 bfr[8];
#pragma unroll
      for (int f = 0; f < 8; ++f)
        bfr[f] = *(const bf16x8*)(wb + (size_t)n * DD + f * 32 + qd * 8);
      f32x4 c = {0.f, 0.f, 0.f, 0.f};
#pragma unroll
      for (int f = 0; f < 8; ++f)
        c = __builtin_amdgcn_mfma_f32_16x16x32_bf16(afrag[f], bfr[f], c, 0, 0, 0);
#pragma unroll
      for (int rr = 0; rr < 4; ++rr) {
        const size_t o = (r0 + wv * 16 + qd * 4 + rr) * DD + n;
        if (mat == 0) q[o] = c[rr];
        else if (mat == 1) kfb[o] = (bf16)c[rr];
        else vfb[o] = (bf16)c[rr];
      }
    }
  }
}

// ---------------------------------------------------------------------------
// edge_v4: bufA eliminated. Edge A-fragments built in registers from
// direct 16B k-row gathers (A-layout == "8 consecutive channels of neighbor
// m" == a plain global load) minus peq (=pe+q) staged once through LDS.
// All gathers (vfb scalar, kfb 16B) prefetched immediately after the js
// barrier so their HBM latency overlaps emb/sin-cos/pe-MFMA work.
// LDS: peq_s 16.9K + union(emb 6K | hs 16.9K) + js = ~34 KB. 3 barriers
// between phases + js barrier.
// ---------------------------------------------------------------------------
__global__ __launch_bounds__(256, 3) void edge_v4(
    const float* __restrict__ xyz, const float* __restrict__ feats,
    const float* __restrict__ q, const bf16* __restrict__ kfb,
    const bf16* __restrict__ vfb, const int* __restrict__ knn,
    const bf16* __restrict__ w1b, const float* __restrict__ g_b1,
    const bf16* __restrict__ w2b, const float* __restrict__ g_b2,
    const bf16* __restrict__ pwb, const float* __restrict__ pe_b,
    float* __restrict__ res) {
  const int t = threadIdx.x;
  const int lane = t & 63;
  const int wv = t >> 6;
  const int m = lane & 15;
  const int qd = lane >> 4;
  const int row0 = blockIdx.x * PTS;
  const int b = row0 >> 12;

  __shared__ __align__(16) bf16 peq_s[PTS][16][264];
  __shared__ __align__(16) char un_s[PTS * 16 * 264 * 2];  // emb | hs union
  bf16(*hs)[16][264] = (bf16(*)[16][264])un_s;
  bf16(*emb_s)[16][96] = (bf16(*)[16][96])un_s;
  __shared__ int js_s[PTS][16];

  if (t < PTS * 16) js_s[t >> 4][t & 15] = knn[(row0 + (t >> 4)) * KK + (t & 15)];
  __syncthreads();

  // ---- prefetch vfb (phase-E layout) + kfb (A-frag layout) early ----
  float vpe[4][PTS][4];
#pragma unroll
  for (int tt = 0; tt < 4; ++tt) {
    const int n = wv * 64 + tt * 16 + m;
#pragma unroll
    for (int p = 0; p < PTS; ++p)
#pragma unroll
      for (int rr = 0; rr < 4; ++rr)
        vpe[tt][p][rr] =
            (float)vfb[((size_t)(b * NN + js_s[p][qd * 4 + rr])) * DD + n];
  }
  bf16x8 ab[PTS][8];  // holds k-rows now, edges later, h later
#pragma unroll
  for (int p = 0; p < PTS; ++p) {
    const size_t base = ((size_t)(b * NN + js_s[p][m])) * DD;
#pragma unroll
    for (int f = 0; f < 8; ++f)
      ab[p][f] = *(const bf16x8*)(kfb + base + f * 32 + qd * 8);
  }

  // ---- emb fill: thread t -> neighbor k=t>>4, cols (t&15)*6..+5 (pad 96) ----
  const float* xb = xyz + (size_t)b * NN * 3;
  {
    const int k = t >> 4;
    const int c0 = (t & 15) * 6;
#pragma unroll
    for (int p = 0; p < PTS; ++p) {
      const int i = (row0 + p) & (NN - 1);
      const int j = js_s[p][k];
#pragma unroll
      for (int cc = 0; cc < 6; ++cc) {
        const int c = c0 + cc;
        float val = 0.f;
        if (c < 33) {
          const int ax = (c < 3) ? c : (c - 3) % 3;
          const float pd = xb[i * 3 + ax] - xb[j * 3 + ax];
          if (c < 3) {
            val = pd;
          } else {
            const int f = (c - 3) / 6;
            const float x = pd * fmaf(7.75f, (float)f, 1.0f);  // linspace(1,32,5)
            val = (((c - 3) % 6) < 3) ? __sinf(x) : __cosf(x);
          }
        }
        emb_s[p][k][c] = (bf16)val;
      }
    }
  }
  __syncthreads();

  // ---- phase B: peq_s = pe + q (bf16 LDS), vpe += pe (exact f32 regs) ----
#pragma unroll
  for (int tt = 0; tt < 4; ++tt) {
    const int n = wv * 64 + tt * 16 + m;
    const bf16x8 b0 = *(const bf16x8*)(pwb + (size_t)n * 64 + qd * 8);
    const bf16x8 b1 = *(const bf16x8*)(pwb + (size_t)n * 64 + 32 + qd * 8);
    const float bias = pe_b[n];
#pragma unroll
    for (int p = 0; p < PTS; ++p) {
      const bf16x8 a0 = *(const bf16x8*)&emb_s[p][m][qd * 8];
      const bf16x8 a1 = *(const bf16x8*)&emb_s[p][m][32 + qd * 8];
      f32x4 c = {bias, bias, bias, bias};
      c = __builtin_amdgcn_mfma_f32_16x16x32_bf16(a0, b0, c, 0, 0, 0);
      c = __builtin_amdgcn_mfma_f32_16x16x32_bf16(a1, b1, c, 0, 0, 0);
      const float qv = q[(size_t)(row0 + p) * DD + n];
#pragma unroll
      for (int rr = 0; rr < 4; ++rr) {
        peq_s[p][qd * 4 + rr][n] = (bf16)(c[rr] + qv);
        vpe[tt][p][rr] += c[rr];
      }
    }
  }
  __syncthreads();  // peq ready; emb reads done (union -> hs safe)

  // ---- edges in regs: ab = bf16(peq_chunk - k_chunk) ----
#pragma unroll
  for (int p = 0; p < PTS; ++p) {
#pragma unroll
    for (int f = 0; f < 8; ++f) {
      const bf16x8 pq = *(const bf16x8*)&peq_s[p][m][f * 32 + qd * 8];
      bf16x8 e;
#pragma unroll
      for (int x = 0; x < 8; ++x) e[x] = (bf16)((float)pq[x] - (float)ab[p][f][x]);
      ab[p][f] = e;
    }
  }
  // ---- layer 1: h = relu(edges @ W1^T + b1) -> hs ----
  for (int tt = 0; tt < 4; ++tt) {
    const int n = wv * 64 + tt * 16 + m;
    bf16x8 bfr[8];
#pragma unroll
    for (int f = 0; f < 8; ++f)
      bfr[f] = *(const bf16x8*)(w1b + (size_t)n * DD + f * 32 + qd * 8);
    const float bias = g_b1[n];
#pragma unroll
    for (int p = 0; p < PTS; ++p) {
      f32x4 c = {bias, bias, bias, bias};
#pragma unroll
      for (int f = 0; f < 8; ++f)
        c = __builtin_amdgcn_mfma_f32_16x16x32_bf16(ab[p][f], bfr[f], c, 0, 0, 0);
#pragma unroll
      for (int rr = 0; rr < 4; ++rr)
        hs[p][qd * 4 + rr][n] = (bf16)fmaxf(c[rr], 0.f);
    }
  }
  __syncthreads();

  // ---- layer 2 + softmax + combine ----
#pragma unroll
  for (int p = 0; p < PTS; ++p)
#pragma unroll
    for (int f = 0; f < 8; ++f)
      ab[p][f] = *(const bf16x8*)&hs[p][m][f * 32 + qd * 8];
#pragma unroll
  for (int tt = 0; tt < 4; ++tt) {
    const int n = wv * 64 + tt * 16 + m;
    bf16x8 bfr[8];
#pragma unroll
    for (int f = 0; f < 8; ++f)
      bfr[f] = *(const bf16x8*)(w2b + (size_t)n * DD + f * 32 + qd * 8);
    const float bias = g_b2[n];
#pragma unroll
    for (int p = 0; p < PTS; ++p) {
      f32x4 c = {bias, bias, bias, bias};
#pragma unroll
      for (int f = 0; f < 8; ++f)
        c = __builtin_amdgcn_mfma_f32_16x16x32_bf16(ab[p][f], bfr[f], c, 0, 0, 0);
      float mx = fmaxf(fmaxf(c[0], c[1]), fmaxf(c[2], c[3]));
      mx = fmaxf(mx, __shfl_xor(mx, 16));
      mx = fmaxf(mx, __shfl_xor(mx, 32));
      float e[4], den = 0.f;
#pragma unroll
      for (int rr = 0; rr < 4; ++rr) {
        e[rr] = __expf(c[rr] - mx);
        den += e[rr];
      }
      den += __shfl_xor(den, 16);
      den += __shfl_xor(den, 32);
      float num = 0.f;
#pragma unroll
      for (int rr = 0; rr < 4; ++rr) num += e[rr] * vpe[tt][p][rr];
      num += __shfl_xor(num, 16);
      num += __shfl_xor(num, 32);
      if (qd == 0) {
        const size_t o = (size_t)(row0 + p) * DD + n;
        res[o] = num / den + feats[o];
      }
    }
  }
}

// ---------------------------------------------------------------------------
// BatchNorm
// ---------------------------------------------------------------------------
__global__ __launch_bounds__(256) void bn_stats(const float* __restrict__ res,
                                                float* __restrict__ sums,
                                                float* __restrict__ sumsq) {
  const int t = threadIdx.x;
  const size_t r0 = (size_t)blockIdx.x * 32;
  float s = 0.f, s2 = 0.f;
  for (int r = 0; r < 32; ++r) {
    const float v = res[(r0 + r) * DD + t];
    s += v;
    s2 += v * v;
  }
  atomicAdd(&sums[t], s);
  atomicAdd(&sumsq[t], s2);
}

__global__ __launch_bounds__(256) void bn_apply(float* __restrict__ out,
                                                const float* __restrict__ sums,
                                                const float* __restrict__ sumsq,
                                                const float* __restrict__ bn_w,
                                                const float* __restrict__ bn_b) {
  const int idx = blockIdx.x * 256 + threadIdx.x;
  const int c = idx & (DD - 1);
  const float inv_n = 1.f / (float)(BB * NN);
  const float mean = sums[c] * inv_n;
  const float var = sumsq[c] * inv_n - mean * mean;
  const float v = out[idx];
  out[idx] = (v - mean) * rsqrtf(var + 1e-5f) * bn_w[c] + bn_b[c];
}

extern "C" void kernel_launch(void* const* d_in, const int* in_sizes, int n_in,
                              void* d_out, int out_size, void* d_ws,
                              size_t ws_size, hipStream_t stream) {
  (void)in_sizes; (void)n_in; (void)out_size; (void)ws_size;
  const float* xyz = (const float*)d_in[0];
  const float* feats = (const float*)d_in[1];
  const float* w_q = (const float*)d_in[2];
  const float* w_k = (const float*)d_in[3];
  const float* w_v = (const float*)d_in[4];
  const float* g_w1 = (const float*)d_in[5];
  const float* g_b1 = (const float*)d_in[6];
  const float* g_w2 = (const float*)d_in[7];
  const float* g_b2 = (const float*)d_in[8];
  const float* pe_w = (const float*)d_in[9];
  const float* pe_b = (const float*)d_in[10];
  const float* bn_w = (const float*)d_in[11];
  const float* bn_b = (const float*)d_in[12];
  float* out = (float*)d_out;

  const int BN = BB * NN;  // 16384
  char* w = (char*)d_ws;
  int* knn = (int*)w;       w += (size_t)BN * KK * 4;
  float* q = (float*)w;     w += (size_t)BN * DD * 4;
  bf16* kfb = (bf16*)w;     w += (size_t)BN * DD * 2;
  bf16* vfb = (bf16*)w;     w += (size_t)BN * DD * 2;
  float* sums = (float*)w;  w += DD * 4;
  float* sumsq = (float*)w; w += DD * 4;
  bf16* wqb = (bf16*)w;     w += (size_t)DD * DD * 2;
  bf16* wkb = (bf16*)w;     w += (size_t)DD * DD * 2;
  bf16* wvb = (bf16*)w;     w += (size_t)DD * DD * 2;
  bf16* w1b = (bf16*)w;     w += (size_t)DD * DD * 2;
  bf16* w2b = (bf16*)w;     w += (size_t)DD * DD * 2;
  bf16* pwb = (bf16*)w;     w += (size_t)DD * 64 * 2;

  prep_kernel<<<DD * DD / 256, 256, 0, stream>>>(w_q, w_k, w_v, g_w1, g_w2,
                                                 pe_w, wqb, wkb, wvb, w1b, w2b,
                                                 pwb, sums);
  knn_v2<<<BN / 4, 256, 0, stream>>>(xyz, knn);
  proj_mfma<<<BN / 64, 256, 0, stream>>>(feats, wqb, wkb, wvb, q, kfb, vfb);
  edge_v4<<<BN / PTS, 256, 0, stream>>>(xyz, feats, q, kfb, vfb, knn, w1b, g_b1,
                                        w2b, g_b2, pwb, pe_b, out);
  bn_stats<<<BN / 32, 256, 0, stream>>>(out, sums, sumsq);
  bn_apply<<<BN, 256, 0, stream>>>(out, sums, sumsq, bn_w, bn_b);
}

// Round 5
// 694.756 us; speedup vs baseline: 1.0976x; 1.0976x over previous
//
#include <hip/hip_runtime.h>

#define BB 4
#define NN 4096
#define DD 256
#define KK 16
#define PTS 2
#define SA 280   // bufA/bufB row stride (bf16): dword 140 % 32 = 12 -> ~2-way
#define SE 104   // emb row stride: dword 52 % 32 = 20 -> ~2-way

typedef __bf16 bf16;
typedef __attribute__((ext_vector_type(8))) __bf16 bf16x8;
typedef __attribute__((ext_vector_type(4))) __bf16 bf16x4;
typedef __attribute__((ext_vector_type(4))) float f32x4;

// ---------------------------------------------------------------------------
// Prep: weights -> bf16; pe_w padded [256][64]; zero bn accumulators.
// ---------------------------------------------------------------------------
__global__ __launch_bounds__(256) void prep_kernel(
    const float* __restrict__ wq, const float* __restrict__ wk,
    const float* __restrict__ wv, const float* __restrict__ w1,
    const float* __restrict__ w2, const float* __restrict__ pw,
    bf16* __restrict__ wqb, bf16* __restrict__ wkb, bf16* __restrict__ wvb,
    bf16* __restrict__ w1b, bf16* __restrict__ w2b, bf16* __restrict__ pwb,
    float* __restrict__ sums) {
  const int idx = blockIdx.x * 256 + threadIdx.x;  // 65536
  wqb[idx] = (bf16)wq[idx];
  wkb[idx] = (bf16)wk[idx];
  wvb[idx] = (bf16)wv[idx];
  w1b[idx] = (bf16)w1[idx];
  w2b[idx] = (bf16)w2[idx];
  if (idx < 256 * 64) {
    const int n = idx >> 6, c = idx & 63;
    pwb[idx] = (c < 33) ? (bf16)pw[n * 33 + c] : (bf16)0.f;
  }
  if (idx < 2 * DD) sums[idx] = 0.f;
}

// ---------------------------------------------------------------------------
// KNN v3: wave per point. Hierarchical selection: 8 group-mins over 8 cands
// each; per round scan 8 group-mins (unfiltered u64 min) + 6-step butterfly;
// only the winner's group rescans (filtered v>lmin), guarded by a
// wave-uniform __ballot branch. Same keys/tie-break as verified v2.
// ---------------------------------------------------------------------------
__global__ __launch_bounds__(256, 2) void knn_v3(const float* __restrict__ xyz,
                                                 int* __restrict__ knn) {
  const int lane = threadIdx.x & 63;
  const int wv = threadIdx.x >> 6;
  const int row = blockIdx.x * 4 + wv;
  const int b = row >> 12, i = row & (NN - 1);
  const float* xb = xyz + (size_t)b * NN * 3;
  const float xi = xb[i * 3 + 0], yi = xb[i * 3 + 1], zi = xb[i * 3 + 2];
  unsigned long long cand[64];
#pragma unroll
  for (int c = 0; c < 64; ++c) {
    const int j = c * 64 + lane;
    const float dx = xi - xb[j * 3 + 0];
    const float dy = yi - xb[j * 3 + 1];
    const float dz = zi - xb[j * 3 + 2];
    const float d = dx * dx + dy * dy + dz * dz;
    const unsigned long long fb = (unsigned long long)(__float_as_uint(d)) + 1ull;
    cand[c] = (fb << 32) | (unsigned int)j;
  }
  unsigned long long gm[8];
#pragma unroll
  for (int g = 0; g < 8; ++g) {
    unsigned long long mn = cand[g * 8];
#pragma unroll
    for (int s = 1; s < 8; ++s)
      if (cand[g * 8 + s] < mn) mn = cand[g * 8 + s];
    gm[g] = mn;
  }
  unsigned int myj = 0u;
  for (int r = 0; r < KK; ++r) {
    unsigned long long lmin = gm[0];
#pragma unroll
    for (int g = 1; g < 8; ++g)
      if (gm[g] < lmin) lmin = gm[g];
#pragma unroll
    for (int off = 1; off < 64; off <<= 1) {
      const unsigned long long o = __shfl_xor(lmin, off);
      if (o < lmin) lmin = o;
    }
    if (lane == r) myj = (unsigned int)lmin;
    // winner's group (exactly one lane/group matches) rescans, filtered
#pragma unroll
    for (int g = 0; g < 8; ++g) {
      if (__ballot(gm[g] == lmin)) {
        unsigned long long nm = ~0ull;
#pragma unroll
        for (int s = 0; s < 8; ++s) {
          const unsigned long long v = cand[g * 8 + s];
          if (v > lmin && v < nm) nm = v;
        }
        if (gm[g] == lmin) gm[g] = nm;
      }
    }
  }
  if (lane < KK) knn[row * KK + lane] = (int)myj;
}

// ---------------------------------------------------------------------------
// proj MFMA: 16 rows/block (1024 blocks for latency hiding). Wave w owns
// cols [w*64, w*64+64) for all 3 matrices. q fp32, k/v bf16.
// ---------------------------------------------------------------------------
__global__ __launch_bounds__(256, 4) void proj_mfma(
    const float* __restrict__ feats, const bf16* __restrict__ wqb,
    const bf16* __restrict__ wkb, const bf16* __restrict__ wvb,
    float* __restrict__ q, bf16* __restrict__ kfb, bf16* __restrict__ vfb) {
  const int t = threadIdx.x;
  const int lane = t & 63, wv = t >> 6;
  const int m = lane & 15, qd = lane >> 4;
  const size_t r0 = (size_t)blockIdx.x * 16;
  __shared__ __align__(16) bf16 fs[16][SA];
  const float4* f4 = (const float4*)(feats + r0 * DD);
#pragma unroll
  for (int i = 0; i < 4; ++i) {
    const int e = i * 256 + t;  // 1024 float4 slots
    const float4 v = f4[e];
    bf16x4 w;
    w[0] = (bf16)v.x; w[1] = (bf16)v.y; w[2] = (bf16)v.z; w[3] = (bf16)v.w;
    *(bf16x4*)&fs[e >> 6][(e & 63) * 4] = w;
  }
  __syncthreads();
  bf16x8 afrag[8];
#pragma unroll
  for (int f = 0; f < 8; ++f)
    afrag[f] = *(const bf16x8*)&fs[m][f * 32 + qd * 8];
  const bf16* wmat[3] = {wqb, wkb, wvb};
  for (int mat = 0; mat < 3; ++mat) {
    const bf16* wb = wmat[mat];
    for (int nt = 0; nt < 4; ++nt) {
      const int n = wv * 64 + nt * 16 + m;
      bf16x8 bfr[8];
#pragma unroll
      for (int f = 0; f < 8; ++f)
        bfr[f] = *(const bf16x8*)(wb + (size_t)n * DD + f * 32 + qd * 8);
      f32x4 c = {0.f, 0.f, 0.f, 0.f};
#pragma unroll
      for (int f = 0; f < 8; ++f)
        c = __builtin_amdgcn_mfma_f32_16x16x32_bf16(afrag[f], bfr[f], c, 0, 0, 0);
#pragma unroll
      for (int rr = 0; rr < 4; ++rr) {
        const size_t o = (r0 + qd * 4 + rr) * DD + n;
        if (mat == 0) q[o] = c[rr];
        else if (mat == 1) kfb[o] = (bf16)c[rr];
        else vfb[o] = (bf16)c[rr];
      }
    }
  }
}

// ---------------------------------------------------------------------------
// edge_v5 = v3 structure (known 371us) + occupancy/conflict fixes:
//  - __launch_bounds__(256,4), LDS ~36KB -> 4 blocks/CU
//  - strides SA=280 (b128 frag reads ~2-way) / SE=104
//  - emb unioned with bufB (h); emb frags hoisted out of tt loop
//  - inline kfb/vfb gathers exactly as v3 (v4 prefetch experiment regressed)
// ---------------------------------------------------------------------------
__global__ __launch_bounds__(256, 4) void edge_v5(
    const float* __restrict__ xyz, const float* __restrict__ feats,
    const float* __restrict__ q, const bf16* __restrict__ kfb,
    const bf16* __restrict__ vfb, const int* __restrict__ knn,
    const bf16* __restrict__ w1b, const float* __restrict__ g_b1,
    const bf16* __restrict__ w2b, const float* __restrict__ g_b2,
    const bf16* __restrict__ pwb, const float* __restrict__ pe_b,
    float* __restrict__ res) {
  const int t = threadIdx.x;
  const int lane = t & 63;
  const int wv = t >> 6;
  const int m = lane & 15;
  const int qd = lane >> 4;
  const int row0 = blockIdx.x * PTS;
  const int b = row0 >> 12;

  __shared__ __align__(16) bf16 bufA[PTS][16][SA];        // edges
  __shared__ __align__(16) char un_s[PTS * 16 * SA * 2];  // emb | bufB(h)
  bf16(*bufB)[16][SA] = (bf16(*)[16][SA])un_s;
  bf16(*emb_s)[16][SE] = (bf16(*)[16][SE])un_s;
  __shared__ int js_s[PTS][16];

  if (t < PTS * 16) js_s[t >> 4][t & 15] = knn[(row0 + (t >> 4)) * KK + (t & 15)];
  __syncthreads();

  // ---- emb fill: thread t -> neighbor k=t>>4, cols (t&15)*6..+5 ----
  const float* xb = xyz + (size_t)b * NN * 3;
  {
    const int k = t >> 4;
    const int c0 = (t & 15) * 6;
#pragma unroll
    for (int p = 0; p < PTS; ++p) {
      const int i = (row0 + p) & (NN - 1);
      const int j = js_s[p][k];
#pragma unroll
      for (int cc = 0; cc < 6; ++cc) {
        const int c = c0 + cc;
        float val = 0.f;
        if (c < 33) {
          const int ax = (c < 3) ? c : (c - 3) % 3;
          const float pd = xb[i * 3 + ax] - xb[j * 3 + ax];
          if (c < 3) {
            val = pd;
          } else {
            const int f = (c - 3) / 6;
            const float x = pd * fmaf(7.75f, (float)f, 1.0f);  // linspace(1,32,5)
            val = (((c - 3) % 6) < 3) ? __sinf(x) : __cosf(x);
          }
        }
        emb_s[p][k][c] = (bf16)val;
      }
    }
  }
  __syncthreads();

  // ---- phase B: pe MFMA -> bufA = q - k + pe ; vpe regs (exact f32) ----
  float vpe[4][PTS][4];
  bf16x8 ea0[PTS], ea1[PTS];
#pragma unroll
  for (int p = 0; p < PTS; ++p) {
    ea0[p] = *(const bf16x8*)&emb_s[p][m][qd * 8];
    ea1[p] = *(const bf16x8*)&emb_s[p][m][32 + qd * 8];
  }
#pragma unroll
  for (int tt = 0; tt < 4; ++tt) {
    const int n = wv * 64 + tt * 16 + m;
    const bf16x8 b0 = *(const bf16x8*)(pwb + (size_t)n * 64 + qd * 8);
    const bf16x8 b1 = *(const bf16x8*)(pwb + (size_t)n * 64 + 32 + qd * 8);
    const float bias = pe_b[n];
#pragma unroll
    for (int p = 0; p < PTS; ++p) {
      f32x4 c = {bias, bias, bias, bias};
      c = __builtin_amdgcn_mfma_f32_16x16x32_bf16(ea0[p], b0, c, 0, 0, 0);
      c = __builtin_amdgcn_mfma_f32_16x16x32_bf16(ea1[p], b1, c, 0, 0, 0);
      const float qv = q[(size_t)(row0 + p) * DD + n];
#pragma unroll
      for (int rr = 0; rr < 4; ++rr) {
        const int krow = qd * 4 + rr;
        const size_t jr = ((size_t)(b * NN + js_s[p][krow])) * DD + n;
        bufA[p][krow][n] = (bf16)(qv - (float)kfb[jr] + c[rr]);
        vpe[tt][p][rr] = (float)vfb[jr] + c[rr];
      }
    }
  }
  __syncthreads();  // bufA ready; emb reads done (union -> bufB safe)

  // ---- layer 1: h = relu(edges @ W1^T + b1), bufA -> bufB ----
  {
    bf16x8 afrag[PTS][8];
#pragma unroll
    for (int p = 0; p < PTS; ++p)
#pragma unroll
      for (int f = 0; f < 8; ++f)
        afrag[p][f] = *(const bf16x8*)&bufA[p][m][f * 32 + qd * 8];
    for (int tt = 0; tt < 4; ++tt) {
      const int n = wv * 64 + tt * 16 + m;
      bf16x8 bfr[8];
#pragma unroll
      for (int f = 0; f < 8; ++f)
        bfr[f] = *(const bf16x8*)(w1b + (size_t)n * DD + f * 32 + qd * 8);
      const float bias = g_b1[n];
#pragma unroll
      for (int p = 0; p < PTS; ++p) {
        f32x4 c = {bias, bias, bias, bias};
#pragma unroll
        for (int f = 0; f < 8; ++f)
          c = __builtin_amdgcn_mfma_f32_16x16x32_bf16(afrag[p][f], bfr[f], c, 0, 0, 0);
#pragma unroll
        for (int rr = 0; rr < 4; ++rr)
          bufB[p][qd * 4 + rr][n] = (bf16)fmaxf(c[rr], 0.f);
      }
    }
  }
  __syncthreads();

  // ---- layer 2 + softmax over k + combine ----
  {
    bf16x8 afrag[PTS][8];
#pragma unroll
    for (int p = 0; p < PTS; ++p)
#pragma unroll
      for (int f = 0; f < 8; ++f)
        afrag[p][f] = *(const bf16x8*)&bufB[p][m][f * 32 + qd * 8];
#pragma unroll
    for (int tt = 0; tt < 4; ++tt) {
      const int n = wv * 64 + tt * 16 + m;
      bf16x8 bfr[8];
#pragma unroll
      for (int f = 0; f < 8; ++f)
        bfr[f] = *(const bf16x8*)(w2b + (size_t)n * DD + f * 32 + qd * 8);
      const float bias = g_b2[n];
#pragma unroll
      for (int p = 0; p < PTS; ++p) {
        f32x4 c = {bias, bias, bias, bias};
#pragma unroll
        for (int f = 0; f < 8; ++f)
          c = __builtin_amdgcn_mfma_f32_16x16x32_bf16(afrag[p][f], bfr[f], c, 0, 0, 0);
        float mx = fmaxf(fmaxf(c[0], c[1]), fmaxf(c[2], c[3]));
        mx = fmaxf(mx, __shfl_xor(mx, 16));
        mx = fmaxf(mx, __shfl_xor(mx, 32));
        float e[4], den = 0.f;
#pragma unroll
        for (int rr = 0; rr < 4; ++rr) {
          e[rr] = __expf(c[rr] - mx);
          den += e[rr];
        }
        den += __shfl_xor(den, 16);
        den += __shfl_xor(den, 32);
        float num = 0.f;
#pragma unroll
        for (int rr = 0; rr < 4; ++rr) num += e[rr] * vpe[tt][p][rr];
        num += __shfl_xor(num, 16);
        num += __shfl_xor(num, 32);
        if (qd == 0) {
          const size_t o = (size_t)(row0 + p) * DD + n;
          res[o] = num / den + feats[o];
        }
      }
    }
  }
}

// ---------------------------------------------------------------------------
// BatchNorm
// ---------------------------------------------------------------------------
__global__ __launch_bounds__(256) void bn_stats(const float* __restrict__ res,
                                                float* __restrict__ sums,
                                                float* __restrict__ sumsq) {
  const int t = threadIdx.x;
  const size_t r0 = (size_t)blockIdx.x * 32;
  float s = 0.f, s2 = 0.f;
  for (int r = 0; r < 32; ++r) {
    const float v = res[(r0 + r) * DD + t];
    s += v;
    s2 += v * v;
  }
  atomicAdd(&sums[t], s);
  atomicAdd(&sumsq[t], s2);
}

__global__ __launch_bounds__(256) void bn_apply(float* __restrict__ out,
                                                const float* __restrict__ sums,
                                                const float* __restrict__ sumsq,
                                                const float* __restrict__ bn_w,
                                                const float* __restrict__ bn_b) {
  const int idx = blockIdx.x * 256 + threadIdx.x;
  const int c = idx & (DD - 1);
  const float inv_n = 1.f / (float)(BB * NN);
  const float mean = sums[c] * inv_n;
  const float var = sumsq[c] * inv_n - mean * mean;
  const float v = out[idx];
  out[idx] = (v - mean) * rsqrtf(var + 1e-5f) * bn_w[c] + bn_b[c];
}

extern "C" void kernel_launch(void* const* d_in, const int* in_sizes, int n_in,
                              void* d_out, int out_size, void* d_ws,
                              size_t ws_size, hipStream_t stream) {
  (void)in_sizes; (void)n_in; (void)out_size; (void)ws_size;
  const float* xyz = (const float*)d_in[0];
  const float* feats = (const float*)d_in[1];
  const float* w_q = (const float*)d_in[2];
  const float* w_k = (const float*)d_in[3];
  const float* w_v = (const float*)d_in[4];
  const float* g_w1 = (const float*)d_in[5];
  const float* g_b1 = (const float*)d_in[6];
  const float* g_w2 = (const float*)d_in[7];
  const float* g_b2 = (const float*)d_in[8];
  const float* pe_w = (const float*)d_in[9];
  const float* pe_b = (const float*)d_in[10];
  const float* bn_w = (const float*)d_in[11];
  const float* bn_b = (const float*)d_in[12];
  float* out = (float*)d_out;

  const int BN = BB * NN;  // 16384
  char* w = (char*)d_ws;
  int* knn = (int*)w;       w += (size_t)BN * KK * 4;
  float* q = (float*)w;     w += (size_t)BN * DD * 4;
  bf16* kfb = (bf16*)w;     w += (size_t)BN * DD * 2;
  bf16* vfb = (bf16*)w;     w += (size_t)BN * DD * 2;
  float* sums = (float*)w;  w += DD * 4;
  float* sumsq = (float*)w; w += DD * 4;
  bf16* wqb = (bf16*)w;     w += (size_t)DD * DD * 2;
  bf16* wkb = (bf16*)w;     w += (size_t)DD * DD * 2;
  bf16* wvb = (bf16*)w;     w += (size_t)DD * DD * 2;
  bf16* w1b = (bf16*)w;     w += (size_t)DD * DD * 2;
  bf16* w2b = (bf16*)w;     w += (size_t)DD * DD * 2;
  bf16* pwb = (bf16*)w;     w += (size_t)DD * 64 * 2;

  prep_kernel<<<DD * DD / 256, 256, 0, stream>>>(w_q, w_k, w_v, g_w1, g_w2,
                                                 pe_w, wqb, wkb, wvb, w1b, w2b,
                                                 pwb, sums);
  knn_v3<<<BN / 4, 256, 0, stream>>>(xyz, knn);
  proj_mfma<<<BN / 16, 256, 0, stream>>>(feats, wqb, wkb, wvb, q, kfb, vfb);
  edge_v5<<<BN / PTS, 256, 0, stream>>>(xyz, feats, q, kfb, vfb, knn, w1b, g_b1,
                                        w2b, g_b2, pwb, pe_b, out);
  bn_stats<<<BN / 32, 256, 0, stream>>>(out, sums, sumsq);
  bn_apply<<<BN, 256, 0, stream>>>(out, sums, sumsq, bn_w, bn_b);
}

// Round 6
// 644.992 us; speedup vs baseline: 1.1823x; 1.0772x over previous
//
#include <hip/hip_runtime.h>

#define BB 4
#define NN 4096
#define DD 256
#define KK 16
#define PTS 2
#define SA 280   // bufA/bufB row stride (bf16)
#define SE 104   // emb row stride
#define SK 264   // kf_s row stride

typedef __bf16 bf16;
typedef __attribute__((ext_vector_type(8))) __bf16 bf16x8;
typedef __attribute__((ext_vector_type(4))) __bf16 bf16x4;
typedef __attribute__((ext_vector_type(4))) float f32x4;

// ---------------------------------------------------------------------------
// Prep: weights -> bf16; pe_w padded [256][64]; zero bn accumulators.
// ---------------------------------------------------------------------------
__global__ __launch_bounds__(256) void prep_kernel(
    const float* __restrict__ wq, const float* __restrict__ wk,
    const float* __restrict__ wv, const float* __restrict__ w1,
    const float* __restrict__ w2, const float* __restrict__ pw,
    bf16* __restrict__ wqb, bf16* __restrict__ wkb, bf16* __restrict__ wvb,
    bf16* __restrict__ w1b, bf16* __restrict__ w2b, bf16* __restrict__ pwb,
    float* __restrict__ sums) {
  const int idx = blockIdx.x * 256 + threadIdx.x;  // 65536
  wqb[idx] = (bf16)wq[idx];
  wkb[idx] = (bf16)wk[idx];
  wvb[idx] = (bf16)wv[idx];
  w1b[idx] = (bf16)w1[idx];
  w2b[idx] = (bf16)w2[idx];
  if (idx < 256 * 64) {
    const int n = idx >> 6, c = idx & 63;
    pwb[idx] = (c < 33) ? (bf16)pw[n * 33 + c] : (bf16)0.f;
  }
  if (idx < 2 * DD) sums[idx] = 0.f;
}

// ---------------------------------------------------------------------------
// KNN v3 (verified R5): wave/point, hierarchical 8x8 group-min selection.
// ---------------------------------------------------------------------------
__global__ __launch_bounds__(256, 2) void knn_v3(const float* __restrict__ xyz,
                                                 int* __restrict__ knn) {
  const int lane = threadIdx.x & 63;
  const int wv = threadIdx.x >> 6;
  const int row = blockIdx.x * 4 + wv;
  const int b = row >> 12, i = row & (NN - 1);
  const float* xb = xyz + (size_t)b * NN * 3;
  const float xi = xb[i * 3 + 0], yi = xb[i * 3 + 1], zi = xb[i * 3 + 2];
  unsigned long long cand[64];
#pragma unroll
  for (int c = 0; c < 64; ++c) {
    const int j = c * 64 + lane;
    const float dx = xi - xb[j * 3 + 0];
    const float dy = yi - xb[j * 3 + 1];
    const float dz = zi - xb[j * 3 + 2];
    const float d = dx * dx + dy * dy + dz * dz;
    const unsigned long long fb = (unsigned long long)(__float_as_uint(d)) + 1ull;
    cand[c] = (fb << 32) | (unsigned int)j;
  }
  unsigned long long gm[8];
#pragma unroll
  for (int g = 0; g < 8; ++g) {
    unsigned long long mn = cand[g * 8];
#pragma unroll
    for (int s = 1; s < 8; ++s)
      if (cand[g * 8 + s] < mn) mn = cand[g * 8 + s];
    gm[g] = mn;
  }
  unsigned int myj = 0u;
  for (int r = 0; r < KK; ++r) {
    unsigned long long lmin = gm[0];
#pragma unroll
    for (int g = 1; g < 8; ++g)
      if (gm[g] < lmin) lmin = gm[g];
#pragma unroll
    for (int off = 1; off < 64; off <<= 1) {
      const unsigned long long o = __shfl_xor(lmin, off);
      if (o < lmin) lmin = o;
    }
    if (lane == r) myj = (unsigned int)lmin;
#pragma unroll
    for (int g = 0; g < 8; ++g) {
      if (__ballot(gm[g] == lmin)) {
        unsigned long long nm = ~0ull;
#pragma unroll
        for (int s = 0; s < 8; ++s) {
          const unsigned long long v = cand[g * 8 + s];
          if (v > lmin && v < nm) nm = v;
        }
        if (gm[g] == lmin) gm[g] = nm;
      }
    }
  }
  if (lane < KK) knn[row * KK + lane] = (int)myj;
}

// ---------------------------------------------------------------------------
// proj MFMA: 16 rows/block. q now stored bf16 too (read scalar downstream).
// ---------------------------------------------------------------------------
__global__ __launch_bounds__(256, 4) void proj_mfma(
    const float* __restrict__ feats, const bf16* __restrict__ wqb,
    const bf16* __restrict__ wkb, const bf16* __restrict__ wvb,
    bf16* __restrict__ qb, bf16* __restrict__ kfb, bf16* __restrict__ vfb) {
  const int t = threadIdx.x;
  const int lane = t & 63, wv = t >> 6;
  const int m = lane & 15, qd = lane >> 4;
  const size_t r0 = (size_t)blockIdx.x * 16;
  __shared__ __align__(16) bf16 fs[16][SA];
  const float4* f4 = (const float4*)(feats + r0 * DD);
#pragma unroll
  for (int i = 0; i < 4; ++i) {
    const int e = i * 256 + t;  // 1024 float4 slots
    const float4 v = f4[e];
    bf16x4 w;
    w[0] = (bf16)v.x; w[1] = (bf16)v.y; w[2] = (bf16)v.z; w[3] = (bf16)v.w;
    *(bf16x4*)&fs[e >> 6][(e & 63) * 4] = w;
  }
  __syncthreads();
  bf16x8 afrag[8];
#pragma unroll
  for (int f = 0; f < 8; ++f)
    afrag[f] = *(const bf16x8*)&fs[m][f * 32 + qd * 8];
  const bf16* wmat[3] = {wqb, wkb, wvb};
  bf16* omat[3] = {qb, kfb, vfb};
  for (int mat = 0; mat < 3; ++mat) {
    const bf16* wb = wmat[mat];
    for (int nt = 0; nt < 4; ++nt) {
      const int n = wv * 64 + nt * 16 + m;
      bf16x8 bfr[8];
#pragma unroll
      for (int f = 0; f < 8; ++f)
        bfr[f] = *(const bf16x8*)(wb + (size_t)n * DD + f * 32 + qd * 8);
      f32x4 c = {0.f, 0.f, 0.f, 0.f};
#pragma unroll
      for (int f = 0; f < 8; ++f)
        c = __builtin_amdgcn_mfma_f32_16x16x32_bf16(afrag[f], bfr[f], c, 0, 0, 0);
#pragma unroll
      for (int rr = 0; rr < 4; ++rr)
        omat[mat][(r0 + qd * 4 + rr) * DD + n] = (bf16)c[rr];
    }
  }
}

// ---------------------------------------------------------------------------
// edge_v6 = v3 structure at (256,3) [best measured; (256,4) spilled in R5]
//  + kf_s: gathered k-rows staged cooperatively into LDS right after the js
//    barrier (vector 16B loads, 512B-contiguous/row) so HBM gather latency
//    overlaps the emb sin/cos VALU work; phase B reads k from LDS.
//  + SA=280 padding, emb unioned with bufB, q read as bf16.
// LDS: bufA 17.9K + union 17.9K + kf_s 16.9K + js = 51.7K -> 3 blocks/CU.
// VGPR budget rule (R4/R5 lesson): no reg-cached A-frags + vpe together.
// ---------------------------------------------------------------------------
__global__ __launch_bounds__(256, 3) void edge_v6(
    const float* __restrict__ xyz, const float* __restrict__ feats,
    const bf16* __restrict__ qb, const bf16* __restrict__ kfb,
    const bf16* __restrict__ vfb, const int* __restrict__ knn,
    const bf16* __restrict__ w1b, const float* __restrict__ g_b1,
    const bf16* __restrict__ w2b, const float* __restrict__ g_b2,
    const bf16* __restrict__ pwb, const float* __restrict__ pe_b,
    float* __restrict__ res) {
  const int t = threadIdx.x;
  const int lane = t & 63;
  const int wv = t >> 6;
  const int m = lane & 15;
  const int qd = lane >> 4;
  const int row0 = blockIdx.x * PTS;
  const int b = row0 >> 12;

  __shared__ __align__(16) bf16 bufA[PTS][16][SA];        // edges
  __shared__ __align__(16) char un_s[PTS * 16 * SA * 2];  // emb | bufB(h)
  bf16(*bufB)[16][SA] = (bf16(*)[16][SA])un_s;
  bf16(*emb_s)[16][SE] = (bf16(*)[16][SE])un_s;
  __shared__ __align__(16) bf16 kf_s[PTS][16][SK];
  __shared__ int js_s[PTS][16];

  if (t < PTS * 16) js_s[t >> 4][t & 15] = knn[(row0 + (t >> 4)) * KK + (t & 15)];
  __syncthreads();

  // ---- stage gathered k-rows into LDS (overlaps with emb trig below) ----
#pragma unroll
  for (int i = 0; i < 4; ++i) {
    const int e = i * 256 + t;          // 1024 chunks of 16B
    const int p = e >> 9, rem = e & 511;
    const int k = rem >> 5, ch = rem & 31;
    const bf16x8 v =
        *(const bf16x8*)(kfb + ((size_t)(b * NN + js_s[p][k])) * DD + ch * 8);
    *(bf16x8*)&kf_s[p][k][ch * 8] = v;
  }

  // ---- emb fill: thread t -> neighbor k=t>>4, cols (t&15)*6..+5 ----
  const float* xb = xyz + (size_t)b * NN * 3;
  {
    const int k = t >> 4;
    const int c0 = (t & 15) * 6;
#pragma unroll
    for (int p = 0; p < PTS; ++p) {
      const int i = (row0 + p) & (NN - 1);
      const int j = js_s[p][k];
#pragma unroll
      for (int cc = 0; cc < 6; ++cc) {
        const int c = c0 + cc;
        float val = 0.f;
        if (c < 33) {
          const int ax = (c < 3) ? c : (c - 3) % 3;
          const float pd = xb[i * 3 + ax] - xb[j * 3 + ax];
          if (c < 3) {
            val = pd;
          } else {
            const int f = (c - 3) / 6;
            const float x = pd * fmaf(7.75f, (float)f, 1.0f);  // linspace(1,32,5)
            val = (((c - 3) % 6) < 3) ? __sinf(x) : __cosf(x);
          }
        }
        emb_s[p][k][c] = (bf16)val;
      }
    }
  }
  __syncthreads();

  // ---- phase B: pe MFMA -> bufA = q - k + pe ; vpe regs (exact f32) ----
  float vpe[4][PTS][4];
  bf16x8 ea0[PTS], ea1[PTS];
#pragma unroll
  for (int p = 0; p < PTS; ++p) {
    ea0[p] = *(const bf16x8*)&emb_s[p][m][qd * 8];
    ea1[p] = *(const bf16x8*)&emb_s[p][m][32 + qd * 8];
  }
#pragma unroll
  for (int tt = 0; tt < 4; ++tt) {
    const int n = wv * 64 + tt * 16 + m;
    const bf16x8 b0 = *(const bf16x8*)(pwb + (size_t)n * 64 + qd * 8);
    const bf16x8 b1 = *(const bf16x8*)(pwb + (size_t)n * 64 + 32 + qd * 8);
    const float bias = pe_b[n];
#pragma unroll
    for (int p = 0; p < PTS; ++p) {
      f32x4 c = {bias, bias, bias, bias};
      c = __builtin_amdgcn_mfma_f32_16x16x32_bf16(ea0[p], b0, c, 0, 0, 0);
      c = __builtin_amdgcn_mfma_f32_16x16x32_bf16(ea1[p], b1, c, 0, 0, 0);
      const float qv = (float)qb[(size_t)(row0 + p) * DD + n];
#pragma unroll
      for (int rr = 0; rr < 4; ++rr) {
        const int krow = qd * 4 + rr;
        const size_t jr = ((size_t)(b * NN + js_s[p][krow])) * DD + n;
        bufA[p][krow][n] = (bf16)(qv - (float)kf_s[p][krow][n] + c[rr]);
        vpe[tt][p][rr] = (float)vfb[jr] + c[rr];
      }
    }
  }
  __syncthreads();  // bufA ready; emb reads done (union -> bufB safe)

  // ---- layer 1: h = relu(edges @ W1^T + b1), bufA -> bufB ----
  {
    bf16x8 afrag[PTS][8];
#pragma unroll
    for (int p = 0; p < PTS; ++p)
#pragma unroll
      for (int f = 0; f < 8; ++f)
        afrag[p][f] = *(const bf16x8*)&bufA[p][m][f * 32 + qd * 8];
    for (int tt = 0; tt < 4; ++tt) {
      const int n = wv * 64 + tt * 16 + m;
      bf16x8 bfr[8];
#pragma unroll
      for (int f = 0; f < 8; ++f)
        bfr[f] = *(const bf16x8*)(w1b + (size_t)n * DD + f * 32 + qd * 8);
      const float bias = g_b1[n];
#pragma unroll
      for (int p = 0; p < PTS; ++p) {
        f32x4 c = {bias, bias, bias, bias};
#pragma unroll
        for (int f = 0; f < 8; ++f)
          c = __builtin_amdgcn_mfma_f32_16x16x32_bf16(afrag[p][f], bfr[f], c, 0, 0, 0);
#pragma unroll
        for (int rr = 0; rr < 4; ++rr)
          bufB[p][qd * 4 + rr][n] = (bf16)fmaxf(c[rr], 0.f);
      }
    }
  }
  __syncthreads();

  // ---- layer 2 + softmax over k + combine ----
  {
    bf16x8 afrag[PTS][8];
#pragma unroll
    for (int p = 0; p < PTS; ++p)
#pragma unroll
      for (int f = 0; f < 8; ++f)
        afrag[p][f] = *(const bf16x8*)&bufB[p][m][f * 32 + qd * 8];
#pragma unroll
    for (int tt = 0; tt < 4; ++tt) {
      const int n = wv * 64 + tt * 16 + m;
      bf16x8 bfr[8];
#pragma unroll
      for (int f = 0; f < 8; ++f)
        bfr[f] = *(const bf16x8*)(w2b + (size_t)n * DD + f * 32 + qd * 8);
      const float bias = g_b2[n];
#pragma unroll
      for (int p = 0; p < PTS; ++p) {
        f32x4 c = {bias, bias, bias, bias};
#pragma unroll
        for (int f = 0; f < 8; ++f)
          c = __builtin_amdgcn_mfma_f32_16x16x32_bf16(afrag[p][f], bfr[f], c, 0, 0, 0);
        float mx = fmaxf(fmaxf(c[0], c[1]), fmaxf(c[2], c[3]));
        mx = fmaxf(mx, __shfl_xor(mx, 16));
        mx = fmaxf(mx, __shfl_xor(mx, 32));
        float e[4], den = 0.f;
#pragma unroll
        for (int rr = 0; rr < 4; ++rr) {
          e[rr] = __expf(c[rr] - mx);
          den += e[rr];
        }
        den += __shfl_xor(den, 16);
        den += __shfl_xor(den, 32);
        float num = 0.f;
#pragma unroll
        for (int rr = 0; rr < 4; ++rr) num += e[rr] * vpe[tt][p][rr];
        num += __shfl_xor(num, 16);
        num += __shfl_xor(num, 32);
        if (qd == 0) {
          const size_t o = (size_t)(row0 + p) * DD + n;
          res[o] = num / den + feats[o];
        }
      }
    }
  }
}

// ---------------------------------------------------------------------------
// BatchNorm
// ---------------------------------------------------------------------------
__global__ __launch_bounds__(256) void bn_stats(const float* __restrict__ res,
                                                float* __restrict__ sums,
                                                float* __restrict__ sumsq) {
  const int t = threadIdx.x;
  const size_t r0 = (size_t)blockIdx.x * 32;
  float s = 0.f, s2 = 0.f;
  for (int r = 0; r < 32; ++r) {
    const float v = res[(r0 + r) * DD + t];
    s += v;
    s2 += v * v;
  }
  atomicAdd(&sums[t], s);
  atomicAdd(&sumsq[t], s2);
}

__global__ __launch_bounds__(256) void bn_apply(float* __restrict__ out,
                                                const float* __restrict__ sums,
                                                const float* __restrict__ sumsq,
                                                const float* __restrict__ bn_w,
                                                const float* __restrict__ bn_b) {
  const int idx = blockIdx.x * 256 + threadIdx.x;
  const int c = idx & (DD - 1);
  const float inv_n = 1.f / (float)(BB * NN);
  const float mean = sums[c] * inv_n;
  const float var = sumsq[c] * inv_n - mean * mean;
  const float v = out[idx];
  out[idx] = (v - mean) * rsqrtf(var + 1e-5f) * bn_w[c] + bn_b[c];
}

extern "C" void kernel_launch(void* const* d_in, const int* in_sizes, int n_in,
                              void* d_out, int out_size, void* d_ws,
                              size_t ws_size, hipStream_t stream) {
  (void)in_sizes; (void)n_in; (void)out_size; (void)ws_size;
  const float* xyz = (const float*)d_in[0];
  const float* feats = (const float*)d_in[1];
  const float* w_q = (const float*)d_in[2];
  const float* w_k = (const float*)d_in[3];
  const float* w_v = (const float*)d_in[4];
  const float* g_w1 = (const float*)d_in[5];
  const float* g_b1 = (const float*)d_in[6];
  const float* g_w2 = (const float*)d_in[7];
  const float* g_b2 = (const float*)d_in[8];
  const float* pe_w = (const float*)d_in[9];
  const float* pe_b = (const float*)d_in[10];
  const float* bn_w = (const float*)d_in[11];
  const float* bn_b = (const float*)d_in[12];
  float* out = (float*)d_out;

  const int BN = BB * NN;  // 16384
  char* w = (char*)d_ws;
  int* knn = (int*)w;       w += (size_t)BN * KK * 4;
  bf16* qb = (bf16*)w;      w += (size_t)BN * DD * 2;
  bf16* kfb = (bf16*)w;     w += (size_t)BN * DD * 2;
  bf16* vfb = (bf16*)w;     w += (size_t)BN * DD * 2;
  float* sums = (float*)w;  w += DD * 4;
  float* sumsq = (float*)w; w += DD * 4;
  bf16* wqb = (bf16*)w;     w += (size_t)DD * DD * 2;
  bf16* wkb = (bf16*)w;     w += (size_t)DD * DD * 2;
  bf16* wvb = (bf16*)w;     w += (size_t)DD * DD * 2;
  bf16* w1b = (bf16*)w;     w += (size_t)DD * DD * 2;
  bf16* w2b = (bf16*)w;     w += (size_t)DD * DD * 2;
  bf16* pwb = (bf16*)w;     w += (size_t)DD * 64 * 2;

  prep_kernel<<<DD * DD / 256, 256, 0, stream>>>(w_q, w_k, w_v, g_w1, g_w2,
                                                 pe_w, wqb, wkb, wvb, w1b, w2b,
                                                 pwb, sums);
  knn_v3<<<BN / 4, 256, 0, stream>>>(xyz, knn);
  proj_mfma<<<BN / 16, 256, 0, stream>>>(feats, wqb, wkb, wvb, qb, kfb, vfb);
  edge_v6<<<BN / PTS, 256, 0, stream>>>(xyz, feats, qb, kfb, vfb, knn, w1b,
                                        g_b1, w2b, g_b2, pwb, pe_b, out);
  bn_stats<<<BN / 32, 256, 0, stream>>>(out, sums, sumsq);
  bn_apply<<<BN, 256, 0, stream>>>(out, sums, sumsq, bn_w, bn_b);
}